// Round 10
// baseline (122.732 us; speedup 1.0000x reference)
//
#include <hip/hip_runtime.h>
#include <stdint.h>

#define B_    16
#define CIN_  128
#define COUT_ 128
#define H_    64
#define W_    64
#define L_    4096
#define KK_   1152

typedef unsigned short u16;
typedef __bf16 bf16x8 __attribute__((ext_vector_type(8)));
typedef float  floatx4 __attribute__((ext_vector_type(4)));
typedef uint32_t u32x4 __attribute__((ext_vector_type(4)));

typedef const __attribute__((address_space(1))) uint32_t* gptr_t;
typedef __attribute__((address_space(3))) uint32_t*       lptr_t;

__device__ __forceinline__ void async_copy16(const void* g, void* l) {
    // stages 64 lanes x 16 B = 1024 B; LDS dest = wave-uniform base + lane*16
    __builtin_amdgcn_global_load_lds((gptr_t)g, (lptr_t)l, 16, 0, 0);
}

__device__ __forceinline__ u16 f2bf(float f) {
    uint32_t u = __builtin_bit_cast(uint32_t, f);
    uint32_t r = u + 0x7FFFu + ((u >> 16) & 1u);   // round-to-nearest-even
    return (u16)(r >> 16);
}

// ---------------------------------------------------------------------------
// Prep: blocks 0..127  -> mb[o][l] = bias[o] + sum_k mw[o][k]*mask[k][l]
//       blocks 128..191 -> wb2[k][o][c] = bf16(weight[o][c][k])
// ---------------------------------------------------------------------------
__global__ void lmc_prep_kernel(const float* __restrict__ mask, const float* __restrict__ mw,
                                const float* __restrict__ bias, const float* __restrict__ w,
                                float* __restrict__ mb, u16* __restrict__ wb2) {
    const int bid = blockIdx.x, tid = threadIdx.x;
    if (bid < 128) {
        const int o = bid;
        float m[9];
        #pragma unroll
        for (int k = 0; k < 9; ++k) m[k] = mw[o * 9 + k];
        const float bs = bias[o];
        for (int l = tid; l < L_; l += 256) {
            float s = bs;
            #pragma unroll
            for (int k = 0; k < 9; ++k) s += m[k] * mask[k * L_ + l];
            mb[o * L_ + l] = s;
        }
    } else {
        const int base = (bid - 128) * 2304;
        #pragma unroll
        for (int i = 0; i < 9; ++i) {
            const int e = base + i * 256 + tid;        // 0..147455 exact
            const int k = e >> 14;                     // /16384
            const int rem = e & 16383;
            const int o = rem >> 7, c = rem & 127;
            wb2[e] = f2bf(w[(size_t)o * KK_ + c * 9 + k]);
        }
    }
}

// ---------------------------------------------------------------------------
// GEMM: 2 blocks/CU overlap version (LDS = 81,920 B exactly -> 2/CU).
// Block = 128(o) x 128(l) = 2 image rows. Window = 4 rows x 64 cols = 64 KB
// (x-halo columns DELETED: they are all-zero; x-out-of-bounds taps are
// zeroed via the mask-bits AND, with the LDS index clamped >=0 so the read
// stays in allocated LDS). A (wb2) double-buffered at quarter-tap
// (128o x 32c = 8 KB x 2). 512 blocks x 256 thr (4 waves of 64x64) =
// exactly 2 blocks/CU: one block's phase-T / barrier-skew / staging-drain /
// epilogue overlaps the sibling's LDS+MFMA loop — the overlap R6's lockstep
// single-block couldn't provide. 36 quarter-tap steps: stage A(s+1),
// 8 ds_read_b128 + 16 MFMA (setprio), vmcnt(0) + raw s_barrier.
// Window pixel p chunk d stored at slot d^(p&7) (pre-swizzled source /
// ds_write); A row o chunk c stored at slot c^(o&3).
// ---------------------------------------------------------------------------
__global__ __launch_bounds__(256, 2)
void lmc_gemm_kernel(const float* __restrict__ x, const u16* __restrict__ wb2,
                     const float* __restrict__ mask, const float* __restrict__ mb,
                     float* __restrict__ out) {
    __shared__ u16 W_lds[256 * 128];      // 65,536 B: 4 rows x 64 cols x 128c
    __shared__ u16 A_lds[2][128 * 32];    // 2 x 8,192 B quarter-tap [o][c32]

    // XCD-chunked bijective swizzle (512 blocks, 8 XCDs): XCD X gets logical
    // [64X, 64X+64) = 2 whole batches -> x working set 4 MB/XCD, L2-resident.
    const int flat    = blockIdx.x;                  // 0..511
    const int logical = (flat & 7) * 64 + (flat >> 3);
    const int b       = logical >> 5;
    const int lt      = logical & 31;                // 0..31
    const int Y       = lt * 2;                      // first image row of tile
    const int l0      = lt * 128;

    const int tid  = threadIdx.x;
    const int lane = tid & 63;
    const int wv   = tid >> 6;                       // 0..3
    const int wm   = (wv >> 1) * 64;                 // o offset {0,64}
    const int wn   = (wv & 1) * 64;                  // l offset {0,64}
    const int lrow = lane & 15;
    const int quad = lane >> 4;

    // =======================================================================
    // Phase T: build window (image rows Y-1..Y+2, cols 0..63) from x.
    // Per lane: 8 c-rows (one 16-B chunk) x 4 x-cols per wy.
    // =======================================================================
    {
        const int cg    = lane >> 4;                 // 0..3
        const int x0    = (lane & 15) * 4;
        const int cbase = wv * 32 + cg * 8;          // 8 c-rows
        const int d     = wv * 4 + cg;               // c-chunk index 0..15
        const float* xc = x + ((size_t)(b * CIN_ + cbase) * L_) + x0;

        #pragma unroll
        for (int wy = 0; wy < 4; ++wy) {
            const int y = Y - 1 + wy;
            if (y >= 0 && y <= 63) {
                const float* xr = xc + y * 64;
                float4 v[8];
                #pragma unroll
                for (int cr = 0; cr < 8; ++cr)
                    v[cr] = *reinterpret_cast<const float4*>(xr + (size_t)cr * L_);
                #pragma unroll
                for (int jj = 0; jj < 4; ++jj) {
                    const int px   = wy * 64 + x0 + jj;
                    const int slot = d ^ (px & 7);
                    uint4 pk;
                    pk.x = (uint32_t)f2bf(((const float*)&v[0])[jj]) |
                           ((uint32_t)f2bf(((const float*)&v[1])[jj]) << 16);
                    pk.y = (uint32_t)f2bf(((const float*)&v[2])[jj]) |
                           ((uint32_t)f2bf(((const float*)&v[3])[jj]) << 16);
                    pk.z = (uint32_t)f2bf(((const float*)&v[4])[jj]) |
                           ((uint32_t)f2bf(((const float*)&v[5])[jj]) << 16);
                    pk.w = (uint32_t)f2bf(((const float*)&v[6])[jj]) |
                           ((uint32_t)f2bf(((const float*)&v[7])[jj]) << 16);
                    *reinterpret_cast<uint4*>((char*)W_lds + px * 256 + slot * 16) = pk;
                }
            } else {
                const uint4 z = {0u, 0u, 0u, 0u};
                #pragma unroll
                for (int jj = 0; jj < 4; ++jj) {
                    const int px   = wy * 64 + x0 + jj;
                    const int slot = d ^ (px & 7);
                    *reinterpret_cast<uint4*>((char*)W_lds + px * 256 + slot * 16) = z;
                }
            }
        }
    }

    // ---- A staging geometry (per-lane source offsets, step-invariant) ----
    // instr t covers A rows 16t..16t+15; lane l -> row 16t+(l>>2), slot l&3;
    // slot s holds source chunk s^(row&3). Source row stride in wb2 = 256 B.
    const int arow0 = 16 * (wv * 2)     + (lane >> 2);
    const int arow1 = 16 * (wv * 2 + 1) + (lane >> 2);
    const int aslx  = (lane & 3) ^ ((lane >> 2) & 3);
    const uint32_t aoffA0 = (uint32_t)(arow0 * 256 + aslx * 16);
    const uint32_t aoffA1 = (uint32_t)(arow1 * 256 + aslx * 16);

    const char* wb2_c = (const char*)wb2;
    char* A_c = (char*)A_lds;

    // stage A(0) (tap 0, c[0:32)) into buffer 0
    async_copy16(wb2_c + aoffA0, A_c + wv * 2048);
    async_copy16(wb2_c + aoffA1, A_c + wv * 2048 + 1024);

    // ---- per-lane window pixel bases + mask bits (mask AND x-in-bounds) ----
    int pix0[4];
    uint64_t bits = 0;
    #pragma unroll
    for (int j = 0; j < 4; ++j) {
        const int ll = wn + j * 16 + lrow;           // block-local l 0..127
        const int xx = ll & 63;
        pix0[j] = ((ll >> 6) + 1) * 64 + xx;
        const int lg = l0 + ll;
        #pragma unroll
        for (int k = 0; k < 9; ++k) {
            const int dx  = k % 3 - 1;
            const bool ok = (xx + dx >= 0) && (xx + dx < 64) &&
                            (mask[k * L_ + lg] != 0.0f);
            if (ok) bits |= (1ull << (k * 4 + j));
        }
    }

    floatx4 acc[4][4];
    #pragma unroll
    for (int i = 0; i < 4; ++i)
        #pragma unroll
        for (int j = 0; j < 4; ++j)
            acc[i][j] = (floatx4){0.f, 0.f, 0.f, 0.f};

    // phase-T ds_writes + A(0) staging complete, then publish
    asm volatile("s_waitcnt vmcnt(0) lgkmcnt(0)" ::: "memory");
    __builtin_amdgcn_s_barrier();
    asm volatile("" ::: "memory");

    // ---- main loop: 36 quarter-tap steps (tap = s>>2, c-quad = s&3) ----
    int buf = 0;
    for (int s = 0; s < 36; ++s) {
        const int k = s >> 2;
        const int q = s & 3;

        if (s < 35) {
            const int sn   = s + 1;
            const int koff = (sn >> 2) * 32768 + (sn & 3) * 64;
            char* dstb = A_c + (buf ^ 1) * 8192;
            async_copy16(wb2_c + koff + aoffA0, dstb + wv * 2048);
            async_copy16(wb2_c + koff + aoffA1, dstb + wv * 2048 + 1024);
        }

        const int dy = k / 3 - 1;
        const int dx = k - (k / 3) * 3 - 1;
        const int sh = dy * 64 + dx;                 // window pixel shift

        uint32_t kp[4];
        #pragma unroll
        for (int j = 0; j < 4; ++j)
            kp[j] = 0u - (uint32_t)((bits >> (k * 4 + j)) & 1ull);

        const u16* Ac = (const u16*)(A_c + buf * 8192);

        bf16x8 af[4], bf[4];
        #pragma unroll
        for (int i = 0; i < 4; ++i) {
            const int orow = wm + i * 16 + lrow;
            const int slot = quad ^ (lrow & 3);      // orow&3 == lrow&3
            af[i] = *reinterpret_cast<const bf16x8*>(&Ac[orow * 32 + slot * 8]);
        }
        #pragma unroll
        for (int j = 0; j < 4; ++j) {
            int p = pix0[j] + sh;
            p = (p < 0) ? 0 : p;                     // clamp (masked anyway)
            const int slot = (q * 4 + quad) ^ (p & 7);
            bf16x8 v = *reinterpret_cast<const bf16x8*>(&W_lds[p * 128 + slot * 8]);
            u32x4 t = __builtin_bit_cast(u32x4, v);
            t &= kp[j];
            bf[j] = __builtin_bit_cast(bf16x8, t);
        }
        __builtin_amdgcn_s_setprio(1);
        #pragma unroll
        for (int i = 0; i < 4; ++i)
            #pragma unroll
            for (int j = 0; j < 4; ++j)
                acc[i][j] = __builtin_amdgcn_mfma_f32_16x16x32_bf16(
                    af[i], bf[j], acc[i][j], 0, 0, 0);
        __builtin_amdgcn_s_setprio(0);

        if (s < 35) {
            // A(s+1) landed (issued ~1 step ago, L2-hot); publish. The drain
            // stall is covered by the sibling block on this CU.
            asm volatile("s_waitcnt vmcnt(0)" ::: "memory");
            __builtin_amdgcn_s_barrier();
            asm volatile("" ::: "memory");
        }
        buf ^= 1;
    }

    // ---- epilogue: C/D layout col = lane&15 (l), row = quad*4 + r (o) ----
    #pragma unroll
    for (int i = 0; i < 4; ++i) {
        #pragma unroll
        for (int j = 0; j < 4; ++j) {
            const int l = l0 + wn + j * 16 + lrow;
            #pragma unroll
            for (int r = 0; r < 4; ++r) {
                const int o = wm + i * 16 + quad * 4 + r;
                out[((size_t)b * COUT_ + o) * L_ + l] = acc[i][j][r] + mb[o * L_ + l];
            }
        }
    }
}

// ---------------------------------------------------------------------------
extern "C" void kernel_launch(void* const* d_in, const int* in_sizes, int n_in,
                              void* d_out, int out_size, void* d_ws, size_t ws_size,
                              hipStream_t stream) {
    const float* x      = (const float*)d_in[0];
    const float* mask   = (const float*)d_in[1];
    const float* weight = (const float*)d_in[2];
    const float* mw     = (const float*)d_in[3];
    const float* bias   = (const float*)d_in[4];
    float* out = (float*)d_out;

    char* ws = (char*)d_ws;
    u16*   wb2 = (u16*)ws;                      // 294,912 B  [9][128][128] bf16
    float* mb  = (float*)(ws + 294912);         // 2,097,152 B [128][4096] f32

    lmc_prep_kernel<<<192, 256, 0, stream>>>(mask, mw, bias, weight, mb, wb2);
    lmc_gemm_kernel<<<512, 256, 0, stream>>>(x, wb2, mask, mb, out);
}

// Round 11
// 117.428 us; speedup vs baseline: 1.0452x; 1.0452x over previous
//
#include <hip/hip_runtime.h>
#include <stdint.h>

#define B_    16
#define CIN_  128
#define COUT_ 128
#define H_    64
#define W_    64
#define L_    4096
#define KK_   1152

typedef unsigned short u16;
typedef __bf16 bf16x8 __attribute__((ext_vector_type(8)));
typedef float  floatx4 __attribute__((ext_vector_type(4)));
typedef uint32_t u32x4 __attribute__((ext_vector_type(4)));

typedef const __attribute__((address_space(1))) uint32_t* gptr_t;
typedef __attribute__((address_space(3))) uint32_t*       lptr_t;

__device__ __forceinline__ void async_copy16(const void* g, void* l) {
    // stages 64 lanes x 16 B = 1024 B; LDS dest = wave-uniform base + lane*16
    __builtin_amdgcn_global_load_lds((gptr_t)g, (lptr_t)l, 16, 0, 0);
}

__device__ __forceinline__ u16 f2bf(float f) {
    uint32_t u = __builtin_bit_cast(uint32_t, f);
    uint32_t r = u + 0x7FFFu + ((u >> 16) & 1u);   // round-to-nearest-even
    return (u16)(r >> 16);
}

// ---------------------------------------------------------------------------
// Prep: blocks 0..127  -> mb[o][l] = bias[o] + sum_k mw[o][k]*mask[k][l]
//       blocks 128..191 -> wb2[k][o][c] = bf16(weight[o][c][k])
// ---------------------------------------------------------------------------
__global__ void lmc_prep_kernel(const float* __restrict__ mask, const float* __restrict__ mw,
                                const float* __restrict__ bias, const float* __restrict__ w,
                                float* __restrict__ mb, u16* __restrict__ wb2) {
    const int bid = blockIdx.x, tid = threadIdx.x;
    if (bid < 128) {
        const int o = bid;
        float m[9];
        #pragma unroll
        for (int k = 0; k < 9; ++k) m[k] = mw[o * 9 + k];
        const float bs = bias[o];
        for (int l = tid; l < L_; l += 256) {
            float s = bs;
            #pragma unroll
            for (int k = 0; k < 9; ++k) s += m[k] * mask[k * L_ + l];
            mb[o * L_ + l] = s;
        }
    } else {
        const int base = (bid - 128) * 2304;
        #pragma unroll
        for (int i = 0; i < 9; ++i) {
            const int e = base + i * 256 + tid;        // 0..147455 exact
            const int k = e >> 14;                     // /16384
            const int rem = e & 16383;
            const int o = rem >> 7, c = rem & 127;
            wb2[e] = f2bf(w[(size_t)o * KK_ + c * 9 + k]);
        }
    }
}

// ---------------------------------------------------------------------------
// GEMM: R9 structure at 16 WAVES (4 waves/SIMD — the never-achieved axis).
// One 1024-thread block per CU (LDS 150,528 B), 256 blocks, XCD-chunked.
// Block = 128(o) x 256(l) = 4 image rows; window 6x66 px x 128c = 101,376 B
// built in-block from x (phase T, 16-wave split); A (wb2) triple-buffered
// 3 x 16 KB at half-tap granularity, counted vmcnt (1 staging instr per wave
// per step -> in-loop wait vmcnt(1), NEVER 0 until the epilogue step).
// 16 waves = 2(wm) x 8(wn), per-wave 64(o) x 32(l): per step 12 ds_read_b128
// + 16 MFMA per wave — half the R9 per-wave work, double the TLP. Exposed
// per-step latency (the measured ~4K-cycle hole at 2 waves/SIMD) is the
// target; LDS-read floor rises 1.5x (A-frag dup x8) but stays ~11.5 us.
// Swizzles identical to R9 (1.18M conflict-cycles measured — negligible).
// Mask applied as bitwise AND on B-fragments (mask is binary -> exact).
// ---------------------------------------------------------------------------
__global__ __launch_bounds__(1024, 4)
void lmc_gemm_kernel(const float* __restrict__ x, const u16* __restrict__ wb2,
                     const float* __restrict__ mask, const float* __restrict__ mb,
                     float* __restrict__ out) {
    __shared__ u16 W_lds[396 * 128];      // 101,376 B window [pix][c], XOR-8 chunk swizzle
    __shared__ u16 A_lds[3][128 * 64];    // 3 x 16,384 B half-tap A [o][c-half], XOR-8

    // XCD-chunked bijective swizzle (256 blocks, 8 XCDs): XCD X gets logical
    // [32X, 32X+32) = 2 whole batches -> x working set L2-friendly per XCD.
    const int flat    = blockIdx.x;                  // 0..255
    const int logical = (flat & 7) * 32 + (flat >> 3);
    const int b       = logical >> 4;
    const int lt      = logical & 15;
    const int Y       = lt * 4;                      // first image row of tile
    const int l0      = lt * 256;

    const int tid  = threadIdx.x;
    const int lane = tid & 63;
    const int wv   = tid >> 6;                       // 0..15
    const int wm   = (wv >> 3) * 64;                 // o offset {0,64}
    const int wn   = (wv & 7) * 32;                  // l offset {0,32,...,224}
    const int lrow = lane & 15;
    const int quad = lane >> 4;

    // =======================================================================
    // Phase T: build window (image rows Y-1..Y+4, cols with x-halo) from x.
    // 16-wave split: c-group = wv>>1 (8 groups of 16c), wy half = wv&1.
    // =======================================================================
    // x-halo pixels (wx=0 and wx=65, all 6 wy): 12 px * 256 B = 192 uint4
    if (tid < 192) {
        const int h  = tid >> 4;                     // 0..11
        const int px = (h >> 1) * 66 + ((h & 1) ? 65 : 0);
        const uint4 z = {0u, 0u, 0u, 0u};
        *reinterpret_cast<uint4*>((char*)W_lds + px * 256 + (tid & 15) * 16) = z;
    }
    {
        const int cg    = lane >> 4;                 // 0..3 (c-quad in 16)
        const int x0    = (lane & 15) * 4;
        const int cbase = (wv >> 1) * 16 + cg * 4;
        const int d     = (wv >> 1) * 2 + (cg >> 1); // data chunk index (c>>3)
        const int half8 = (cg & 1) * 8;              // byte offset in chunk
        const float* xc = x + ((size_t)(b * CIN_ + cbase) * L_) + x0;

        #pragma unroll
        for (int wyi = 0; wyi < 3; ++wyi) {
            const int wy  = (wv & 1) * 3 + wyi;
            const int y   = Y - 1 + wy;
            const int px0 = wy * 66 + x0 + 1;
            if (y >= 0 && y <= 63) {
                const float* xr = xc + y * 64;
                float4 v0 = *reinterpret_cast<const float4*>(xr);
                float4 v1 = *reinterpret_cast<const float4*>(xr + L_);
                float4 v2 = *reinterpret_cast<const float4*>(xr + 2 * L_);
                float4 v3 = *reinterpret_cast<const float4*>(xr + 3 * L_);
                const float* p0 = (const float*)&v0;
                const float* p1 = (const float*)&v1;
                const float* p2 = (const float*)&v2;
                const float* p3 = (const float*)&v3;
                #pragma unroll
                for (int j = 0; j < 4; ++j) {
                    const int px   = px0 + j;
                    const int slot = d ^ (px & 7);
                    uint2 pk;
                    pk.x = (uint32_t)f2bf(p0[j]) | ((uint32_t)f2bf(p1[j]) << 16);
                    pk.y = (uint32_t)f2bf(p2[j]) | ((uint32_t)f2bf(p3[j]) << 16);
                    *reinterpret_cast<uint2*>((char*)W_lds + px * 256 + slot * 16 + half8) = pk;
                }
            } else {
                const uint2 z2 = {0u, 0u};
                #pragma unroll
                for (int j = 0; j < 4; ++j) {
                    const int px   = px0 + j;
                    const int slot = d ^ (px & 7);
                    *reinterpret_cast<uint2*>((char*)W_lds + px * 256 + slot * 16 + half8) = z2;
                }
            }
        }
    }

    // ---- A staging geometry: 16 waves, 1 instr/wave/step (16 KB total) ----
    // LDS A row o (128 B = 8 chunks): slot s holds source chunk s^(o&7).
    // instr t = wv covers rows 8wv..8wv+7; lane l -> row 8wv+(l>>3), slot l&7.
    const char* wb2_c = (const char*)wb2;
    char* A_c = (char*)A_lds;
    const int ao  = (lane >> 3);
    const int ach = (lane & 7) ^ (ao & 7);
    const int aoff0 = (8 * wv + ao) * 256 + ach * 16;
    // stage A(0)->buf0, A(1)->buf1 (half-step gn: koff = (gn>>1)*32768+(gn&1)*128)
    async_copy16(wb2_c + aoff0,       A_c + wv * 1024);
    async_copy16(wb2_c + 128 + aoff0, A_c + 16384 + wv * 1024);

    // ---- per-lane window pixel bases + mask bit-pack (18 bits) ----
    int pix0[2];
    uint32_t bits = 0;
    #pragma unroll
    for (int j = 0; j < 2; ++j) {
        const int ll = wn + j * 16 + lrow;           // block-local l 0..255
        pix0[j] = ((ll >> 6) + 1) * 66 + (ll & 63) + 1;
        const int lg = l0 + ll;
        #pragma unroll
        for (int k = 0; k < 9; ++k)
            if (mask[k * L_ + lg] != 0.0f) bits |= (1u << (k * 2 + j));
    }

    floatx4 acc[4][2];
    #pragma unroll
    for (int i = 0; i < 4; ++i)
        #pragma unroll
        for (int j = 0; j < 2; ++j)
            acc[i][j] = (floatx4){0.f, 0.f, 0.f, 0.f};

    // phase-T ds_writes done; my A(0) slice done (A(1) may stay in flight)
    asm volatile("s_waitcnt vmcnt(1) lgkmcnt(0)" ::: "memory");
    __builtin_amdgcn_s_barrier();
    asm volatile("" ::: "memory");   // no ds_read hoisting above the barrier

    // ---- main loop: 18 half-steps (tap = g>>1, c-half = g&1) ----
    int bufr = 0;   // buffer holding A(g)
    int bufw = 2;   // buffer to receive A(g+2)
    for (int g = 0; g < 18; ++g) {
        const int k = g >> 1;

        // issue A(g+2) (stays in flight across this step's end barrier)
        if (g < 16) {
            const int gn   = g + 2;
            const int koff = (gn >> 1) * 32768 + (gn & 1) * 128;
            async_copy16(wb2_c + koff + aoff0, A_c + bufw * 16384 + wv * 1024);
        }

        const int sh = (k / 3 - 1) * 66 + (k % 3) - 1;   // window pixel shift
        uint32_t kp[2];
        #pragma unroll
        for (int j = 0; j < 2; ++j)
            kp[j] = 0u - (uint32_t)((bits >> (k * 2 + j)) & 1u);

        const u16* Ac = (const u16*)(A_c + bufr * 16384);

        #pragma unroll
        for (int ksl = 0; ksl < 2; ++ksl) {              // 32-c slices in half
            const int ksg = (g & 1) * 2 + ksl;           // global c-chunk quad
            bf16x8 af[4], bf[2];
            #pragma unroll
            for (int i = 0; i < 4; ++i) {
                const int orow = wm + i * 16 + lrow;
                const int slot = (ksl * 4 + quad) ^ (orow & 7);
                af[i] = *reinterpret_cast<const bf16x8*>(&Ac[orow * 64 + slot * 8]);
            }
            #pragma unroll
            for (int j = 0; j < 2; ++j) {
                const int pix  = pix0[j] + sh;
                const int slot = (ksg * 4 + quad) ^ (pix & 7);
                bf16x8 v = *reinterpret_cast<const bf16x8*>(&W_lds[pix * 128 + slot * 8]);
                u32x4 t = __builtin_bit_cast(u32x4, v);
                t &= kp[j];
                bf[j] = __builtin_bit_cast(bf16x8, t);
            }
            __builtin_amdgcn_s_setprio(1);
            #pragma unroll
            for (int i = 0; i < 4; ++i)
                #pragma unroll
                for (int j = 0; j < 2; ++j)
                    acc[i][j] = __builtin_amdgcn_mfma_f32_16x16x32_bf16(
                        af[i], bf[j], acc[i][j], 0, 0, 0);
            __builtin_amdgcn_s_setprio(0);
        }

        // end of step: my A(g+1) instr provably done (vmcnt(1) leaves only
        // A(g+2) in flight); publish via raw barrier — no vmcnt(0) in-loop
        if (g < 16) {
            asm volatile("s_waitcnt vmcnt(1)" ::: "memory");
            __builtin_amdgcn_s_barrier();
            asm volatile("" ::: "memory");
        } else if (g == 16) {
            asm volatile("s_waitcnt vmcnt(0)" ::: "memory");
            __builtin_amdgcn_s_barrier();
            asm volatile("" ::: "memory");
        }
        bufr = (bufr == 2) ? 0 : bufr + 1;
        bufw = (bufw == 2) ? 0 : bufw + 1;
    }

    // ---- epilogue: C/D layout col = lane&15 (l), row = quad*4 + r (o) ----
    #pragma unroll
    for (int i = 0; i < 4; ++i) {
        #pragma unroll
        for (int j = 0; j < 2; ++j) {
            const int l = l0 + wn + j * 16 + lrow;
            #pragma unroll
            for (int r = 0; r < 4; ++r) {
                const int o = wm + i * 16 + quad * 4 + r;
                out[((size_t)b * COUT_ + o) * L_ + l] = acc[i][j][r] + mb[o * L_ + l];
            }
        }
    }
}

// ---------------------------------------------------------------------------
extern "C" void kernel_launch(void* const* d_in, const int* in_sizes, int n_in,
                              void* d_out, int out_size, void* d_ws, size_t ws_size,
                              hipStream_t stream) {
    const float* x      = (const float*)d_in[0];
    const float* mask   = (const float*)d_in[1];
    const float* weight = (const float*)d_in[2];
    const float* mw     = (const float*)d_in[3];
    const float* bias   = (const float*)d_in[4];
    float* out = (float*)d_out;

    char* ws = (char*)d_ws;
    u16*   wb2 = (u16*)ws;                      // 294,912 B  [9][128][128] bf16
    float* mb  = (float*)(ws + 294912);         // 2,097,152 B [128][4096] f32

    lmc_prep_kernel<<<192, 256, 0, stream>>>(mask, mw, bias, weight, mb, wb2);
    lmc_gemm_kernel<<<256, 1024, 0, stream>>>(x, wb2, mask, mb, out);
}

// Round 12
// 117.425 us; speedup vs baseline: 1.0452x; 1.0000x over previous
//
#include <hip/hip_runtime.h>
#include <stdint.h>

#define B_    16
#define CIN_  128
#define COUT_ 128
#define H_    64
#define W_    64
#define L_    4096
#define KK_   1152

typedef unsigned short u16;
typedef __bf16 bf16x8 __attribute__((ext_vector_type(8)));
typedef float  floatx4 __attribute__((ext_vector_type(4)));
typedef uint32_t u32x4 __attribute__((ext_vector_type(4)));

typedef const __attribute__((address_space(1))) uint32_t* gptr_t;
typedef __attribute__((address_space(3))) uint32_t*       lptr_t;

__device__ __forceinline__ void async_copy16(const void* g, void* l) {
    // stages 64 lanes x 16 B = 1024 B; LDS dest = wave-uniform base + lane*16
    __builtin_amdgcn_global_load_lds((gptr_t)g, (lptr_t)l, 16, 0, 0);
}

__device__ __forceinline__ u16 f2bf(float f) {
    uint32_t u = __builtin_bit_cast(uint32_t, f);
    uint32_t r = u + 0x7FFFu + ((u >> 16) & 1u);   // round-to-nearest-even
    return (u16)(r >> 16);
}

// ---------------------------------------------------------------------------
// Prep: blocks 0..127  -> mb[o][l] = bias[o] + sum_k mw[o][k]*mask[k][l]
//       blocks 128..191 -> wb2[k][o][c] = bf16(weight[o][c][k])
// ---------------------------------------------------------------------------
__global__ void lmc_prep_kernel(const float* __restrict__ mask, const float* __restrict__ mw,
                                const float* __restrict__ bias, const float* __restrict__ w,
                                float* __restrict__ mb, u16* __restrict__ wb2) {
    const int bid = blockIdx.x, tid = threadIdx.x;
    if (bid < 128) {
        const int o = bid;
        float m[9];
        #pragma unroll
        for (int k = 0; k < 9; ++k) m[k] = mw[o * 9 + k];
        const float bs = bias[o];
        for (int l = tid; l < L_; l += 256) {
            float s = bs;
            #pragma unroll
            for (int k = 0; k < 9; ++k) s += m[k] * mask[k * L_ + l];
            mb[o * L_ + l] = s;
        }
    } else {
        const int base = (bid - 128) * 2304;
        #pragma unroll
        for (int i = 0; i < 9; ++i) {
            const int e = base + i * 256 + tid;        // 0..147455 exact
            const int k = e >> 14;                     // /16384
            const int rem = e & 16383;
            const int o = rem >> 7, c = rem & 127;
            wb2[e] = f2bf(w[(size_t)o * KK_ + c * 9 + k]);
        }
    }
}

// ---------------------------------------------------------------------------
// GEMM: FULL-TAP steps — 9 barriers instead of 18/36 (the axis all prior
// variants shared). LDS = 163,840 B EXACTLY (160 KB/CU max):
//   window 6 rows x 64 cols x 128c = 98,304 B (x-halo columns deleted;
//   x-OOB taps folded into mask bits + clamped LDS index, proven in R10)
//   A (wb2) double-buffered at full-tap: 2 x 32,768 B.
// 256 blocks x 512 thr (8 waves of 64x64, 2m x 4n — R9's balanced split),
// 1 block/CU, XCD-chunked swizzle. Per step: stage A(k+1) (4 instrs/wave,
// ~1500 cy before its wait -> covered), 4 ks-slices of {4 af + 4 bf ds_read
// + 16 MFMA (setprio)}, vmcnt(0) + raw s_barrier. Per-step overhead (barrier
// skew + post-barrier latency + staging wait) paid 9x not 18x, with 2x the
// MFMA per step to cover it. Mask applied as bitwise AND on B-fragments.
// ---------------------------------------------------------------------------
__global__ __launch_bounds__(512, 2)
void lmc_gemm_kernel(const float* __restrict__ x, const u16* __restrict__ wb2,
                     const float* __restrict__ mask, const float* __restrict__ mb,
                     float* __restrict__ out) {
    __shared__ u16 W_lds[384 * 128];      // 98,304 B window [pix][c], XOR-8 chunk swizzle
    __shared__ u16 A_lds[2][128 * 128];   // 2 x 32,768 B full-tap A [o][c], XOR-8

    // XCD-chunked bijective swizzle (256 blocks, 8 XCDs): XCD X gets logical
    // [32X, 32X+32) = 2 whole batches -> x working set L2-friendly per XCD.
    const int flat    = blockIdx.x;                  // 0..255
    const int logical = (flat & 7) * 32 + (flat >> 3);
    const int b       = logical >> 4;
    const int lt      = logical & 15;
    const int Y       = lt * 4;                      // first image row of tile
    const int l0      = lt * 256;

    const int tid  = threadIdx.x;
    const int lane = tid & 63;
    const int wv   = tid >> 6;                       // 0..7
    const int wm   = (wv >> 2) * 64;                 // o offset {0,64}
    const int wn   = (wv & 3) * 64;                  // l offset {0,64,128,192}
    const int lrow = lane & 15;
    const int quad = lane >> 4;

    // =======================================================================
    // Phase T: build window (image rows Y-1..Y+4, cols 0..63 only) from x.
    // Wave wv owns c-group [16wv, 16wv+16); per lane 4 c-rows x 4 x-cols.
    // =======================================================================
    {
        const int cg    = lane >> 4;                 // 0..3 (c-quad in 16)
        const int x0    = (lane & 15) * 4;
        const int cbase = wv * 16 + cg * 4;
        const int d     = wv * 2 + (cg >> 1);        // data chunk index (c>>3)
        const int half8 = (cg & 1) * 8;              // byte offset in chunk
        const float* xc = x + ((size_t)(b * CIN_ + cbase) * L_) + x0;

        #pragma unroll
        for (int wy = 0; wy < 6; ++wy) {
            const int y   = Y - 1 + wy;
            const int px0 = wy * 64 + x0;
            if (y >= 0 && y <= 63) {
                const float* xr = xc + y * 64;
                float4 v0 = *reinterpret_cast<const float4*>(xr);
                float4 v1 = *reinterpret_cast<const float4*>(xr + L_);
                float4 v2 = *reinterpret_cast<const float4*>(xr + 2 * L_);
                float4 v3 = *reinterpret_cast<const float4*>(xr + 3 * L_);
                const float* p0 = (const float*)&v0;
                const float* p1 = (const float*)&v1;
                const float* p2 = (const float*)&v2;
                const float* p3 = (const float*)&v3;
                #pragma unroll
                for (int j = 0; j < 4; ++j) {
                    const int px   = px0 + j;
                    const int slot = d ^ (px & 7);
                    uint2 pk;
                    pk.x = (uint32_t)f2bf(p0[j]) | ((uint32_t)f2bf(p1[j]) << 16);
                    pk.y = (uint32_t)f2bf(p2[j]) | ((uint32_t)f2bf(p3[j]) << 16);
                    *reinterpret_cast<uint2*>((char*)W_lds + px * 256 + slot * 16 + half8) = pk;
                }
            } else {
                const uint2 z2 = {0u, 0u};
                #pragma unroll
                for (int j = 0; j < 4; ++j) {
                    const int px   = px0 + j;
                    const int slot = d ^ (px & 7);
                    *reinterpret_cast<uint2*>((char*)W_lds + px * 256 + slot * 16 + half8) = z2;
                }
            }
        }
    }

    // ---- A staging geometry: 4 instrs/wave/tap (32 KB / 8 waves / 1 KB) ----
    // LDS A row o (256 B = 16 chunks): slot s holds source chunk s^(o&7).
    // instr (wv,ti) covers rows 16wv+4ti .. +3; lane l -> row +(l>>4), slot l&15.
    const char* wb2_c = (const char*)wb2;
    char* A_c = (char*)A_lds;
    uint32_t aoff[4];
    #pragma unroll
    for (int ti = 0; ti < 4; ++ti) {
        const int r  = 16 * wv + 4 * ti + (lane >> 4);
        const int sc = (lane & 15) ^ (r & 7);
        aoff[ti] = (uint32_t)(r * 256 + sc * 16);
    }
    // stage A(0) -> buffer 0
    #pragma unroll
    for (int ti = 0; ti < 4; ++ti)
        async_copy16(wb2_c + aoff[ti], A_c + (wv * 4 + ti) * 1024);

    // ---- per-lane window pixel bases + mask bits (mask AND x-in-bounds) ----
    int pix0[4];
    uint64_t bits = 0;
    #pragma unroll
    for (int j = 0; j < 4; ++j) {
        const int ll = wn + j * 16 + lrow;           // block-local l 0..255
        const int xx = ll & 63;
        pix0[j] = ((ll >> 6) + 1) * 64 + xx;
        const int lg = l0 + ll;
        #pragma unroll
        for (int k = 0; k < 9; ++k) {
            const int dx  = k % 3 - 1;
            const bool ok = (xx + dx >= 0) && (xx + dx < 64) &&
                            (mask[k * L_ + lg] != 0.0f);
            if (ok) bits |= (1ull << (k * 4 + j));
        }
    }

    floatx4 acc[4][4];
    #pragma unroll
    for (int i = 0; i < 4; ++i)
        #pragma unroll
        for (int j = 0; j < 4; ++j)
            acc[i][j] = (floatx4){0.f, 0.f, 0.f, 0.f};

    // phase-T ds_writes + A(0) staging complete, then publish
    asm volatile("s_waitcnt vmcnt(0) lgkmcnt(0)" ::: "memory");
    __builtin_amdgcn_s_barrier();
    asm volatile("" ::: "memory");   // no ds_read hoisting above the barrier

    // ---- main loop: 9 FULL-TAP steps ----
    for (int k = 0; k < 9; ++k) {
        // stage A(k+1) into the other buffer (readers of it finished at the
        // barrier ending step k-1; our 4 instrs drain at this step's end,
        // ~1500 cy after issue -> covered by the 64 MFMAs)
        if (k < 8) {
            const int koff = (k + 1) * 32768;
            char* dstb = A_c + ((k + 1) & 1) * 32768;
            #pragma unroll
            for (int ti = 0; ti < 4; ++ti)
                async_copy16(wb2_c + koff + aoff[ti], dstb + (wv * 4 + ti) * 1024);
        }

        const int dy = k / 3 - 1;
        const int dx = k - (k / 3) * 3 - 1;
        const int sh = dy * 64 + dx;                 // window pixel shift

        uint32_t kp[4];
        #pragma unroll
        for (int j = 0; j < 4; ++j)
            kp[j] = 0u - (uint32_t)((bits >> (k * 4 + j)) & 1ull);

        const u16* Ac = (const u16*)(A_c + (k & 1) * 32768);

        #pragma unroll
        for (int ks = 0; ks < 4; ++ks) {             // 32-c slices of the tap
            bf16x8 af[4], bf[4];
            #pragma unroll
            for (int i = 0; i < 4; ++i) {
                const int orow = wm + i * 16 + lrow;
                const int slot = (ks * 4 + quad) ^ (orow & 7);
                af[i] = *reinterpret_cast<const bf16x8*>(&Ac[orow * 128 + slot * 8]);
            }
            #pragma unroll
            for (int j = 0; j < 4; ++j) {
                int p = pix0[j] + sh;
                p = (p < 0) ? 0 : p;                 // OOB taps masked anyway
                p = (p > 383) ? 383 : p;
                const int slot = (ks * 4 + quad) ^ (p & 7);
                bf16x8 v = *reinterpret_cast<const bf16x8*>(&W_lds[p * 128 + slot * 8]);
                u32x4 t = __builtin_bit_cast(u32x4, v);
                t &= kp[j];
                bf[j] = __builtin_bit_cast(bf16x8, t);
            }
            __builtin_amdgcn_s_setprio(1);
            #pragma unroll
            for (int i = 0; i < 4; ++i)
                #pragma unroll
                for (int j = 0; j < 4; ++j)
                    acc[i][j] = __builtin_amdgcn_mfma_f32_16x16x32_bf16(
                        af[i], bf[j], acc[i][j], 0, 0, 0);
            __builtin_amdgcn_s_setprio(0);
        }

        // end of step: own A(k+1) staging done, publish buffer swap
        if (k < 8) {
            asm volatile("s_waitcnt vmcnt(0)" ::: "memory");
            __builtin_amdgcn_s_barrier();
            asm volatile("" ::: "memory");
        }
    }

    // ---- epilogue: C/D layout col = lane&15 (l), row = quad*4 + r (o) ----
    #pragma unroll
    for (int i = 0; i < 4; ++i) {
        #pragma unroll
        for (int j = 0; j < 4; ++j) {
            const int l = l0 + wn + j * 16 + lrow;
            #pragma unroll
            for (int r = 0; r < 4; ++r) {
                const int o = wm + i * 16 + quad * 4 + r;
                out[((size_t)b * COUT_ + o) * L_ + l] = acc[i][j][r] + mb[o * L_ + l];
            }
        }
    }
}

// ---------------------------------------------------------------------------
extern "C" void kernel_launch(void* const* d_in, const int* in_sizes, int n_in,
                              void* d_out, int out_size, void* d_ws, size_t ws_size,
                              hipStream_t stream) {
    const float* x      = (const float*)d_in[0];
    const float* mask   = (const float*)d_in[1];
    const float* weight = (const float*)d_in[2];
    const float* mw     = (const float*)d_in[3];
    const float* bias   = (const float*)d_in[4];
    float* out = (float*)d_out;

    char* ws = (char*)d_ws;
    u16*   wb2 = (u16*)ws;                      // 294,912 B  [9][128][128] bf16
    float* mb  = (float*)(ws + 294912);         // 2,097,152 B [128][4096] f32

    lmc_prep_kernel<<<192, 256, 0, stream>>>(mask, mw, bias, weight, mb, wb2);
    lmc_gemm_kernel<<<256, 512, 0, stream>>>(x, wb2, mask, mb, out);
}